// Round 2
// baseline (35188.535 us; speedup 1.0000x reference)
//
#include <hip/hip_runtime.h>
#include <cstdint>
#include <cstddef>

// ---------------- problem constants ----------------
#define TSTEPS 2000
#define NB     256      // batch
#define HID    128
#define CIN    14
#define NGRP   64       // row groups
#define RG     4        // rows per group
#define BPG    4        // blocks per group (h-quarters, each does L1+L2)

// ---------------- workspace layout (bytes) ----------------
#define OFF_CNT   0ull                     // 64 counters * 128B = 8192
#define OFF_M1WS  8192ull                  // [2][64][4][128] f32 = 262144
#define OFF_M2WS  (OFF_M1WS + 262144ull)   // [2][64][4][128] f32
#define OFF_SPKW  (OFF_M2WS + 262144ull)   // [2][64][4][4] u32 = 8192
#define OFF_FEAT  (OFF_SPKW + 8192ull)     // [256][128] f32 = 131072
#define OFF_AB    (OFF_FEAT + 131072ull)   // a[64], b[64] = 512
#define OFF_PART  (OFF_AB   + 512ull)      // [2304][64][2] f32 = 1179648
#define OFF_MASK  (OFF_PART + 1179648ull)  // [2000][256] u64 = 4096000
#define ZERO_WORDS 133120                  // counters + m1ws + m2ws

// ============================================================
// K0: zero counters + state buffers (every launch, for graph replay)
// ============================================================
__global__ __launch_bounds__(256) void k0_zero(unsigned* ws) {
  int i = blockIdx.x * 256 + threadIdx.x;
  if (i < ZERO_WORDS) ws[i] = 0u;
}

// ============================================================
// K1: conv1d -> per-(b,tile) partial sum/sumsq for BN
// ============================================================
__global__ __launch_bounds__(256) void k1_stats(const float* __restrict__ x,
                                                const float* __restrict__ cw,
                                                float* __restrict__ part) {
  __shared__ float xLds[244 * CIN];
  __shared__ float cwLds[64 * 70];
  __shared__ float red[2][4][64];
  const int b = blockIdx.x, tile = blockIdx.y;
  const int base = tile * 240;
  for (int f = threadIdx.x; f < 244 * CIN; f += 256) {
    int u = f / CIN, ci = f - u * CIN;
    int tp = base + u - 2;
    xLds[f] = (tp >= 0 && tp < TSTEPS) ? x[((size_t)tp * NB + b) * CIN + ci] : 0.0f;
  }
  for (int f = threadIdx.x; f < 64 * 70; f += 256) cwLds[f] = cw[f];
  __syncthreads();

  const int co = threadIdx.x & 63, tq = threadIdx.x >> 6;
  float cwr[70];
#pragma unroll
  for (int s = 0; s < 70; ++s) cwr[s] = cwLds[co * 70 + s];
  float xw[5][CIN];
  const int u0 = tq * 60;
#pragma unroll
  for (int r = 0; r < 4; ++r)
#pragma unroll
    for (int ci = 0; ci < CIN; ++ci) xw[r][ci] = xLds[(u0 + r) * CIN + ci];

  float s1 = 0.0f, s2 = 0.0f;
  const int tbase = base + tq * 60;
  for (int i5 = 0; i5 < 60; i5 += 5) {
#pragma unroll
    for (int s = 0; s < 5; ++s) {
#pragma unroll
      for (int ci = 0; ci < CIN; ++ci)
        xw[(s + 4) % 5][ci] = xLds[(u0 + i5 + s + 4) * CIN + ci];
      float y = 0.0f;
#pragma unroll
      for (int kk = 0; kk < 5; ++kk)
#pragma unroll
        for (int ci = 0; ci < CIN; ++ci)
          y += xw[(s + kk) % 5][ci] * cwr[ci * 5 + kk];
      if (tbase + i5 + s < TSTEPS) { s1 += y; s2 += y * y; }
    }
  }
  red[0][tq][co] = s1; red[1][tq][co] = s2;
  __syncthreads();
  if (threadIdx.x < 64) {
    float a1 = red[0][0][co] + red[0][1][co] + red[0][2][co] + red[0][3][co];
    float a2 = red[1][0][co] + red[1][1][co] + red[1][2][co] + red[1][3][co];
    int blk = tile * NB + b;
    part[blk * 128 + co * 2 + 0] = a1;
    part[blk * 128 + co * 2 + 1] = a2;
  }
}

// K1b: deterministic fixed-order reduction of partials -> a[co], b[co]
__global__ __launch_bounds__(256) void k1b_reduce(const float* __restrict__ gamma,
                           const float* __restrict__ beta,
                           const float* __restrict__ part, float* __restrict__ ab) {
  __shared__ float red[2][4][64];
  const int co = threadIdx.x & 63, pt = threadIdx.x >> 6;
  float s1 = 0.0f, s2 = 0.0f;
  for (int blk = pt * 576; blk < pt * 576 + 576; ++blk) {
    s1 += part[blk * 128 + co * 2 + 0];
    s2 += part[blk * 128 + co * 2 + 1];
  }
  red[0][pt][co] = s1; red[1][pt][co] = s2;
  __syncthreads();
  if (threadIdx.x < 64) {
    float a1 = red[0][0][co] + red[0][1][co] + red[0][2][co] + red[0][3][co];
    float a2 = red[1][0][co] + red[1][1][co] + red[1][2][co] + red[1][3][co];
    const float N = (float)TSTEPS * (float)NB;
    float mu = a1 / N;
    float var = a2 / N - mu * mu;
    float rstd = 1.0f / sqrtf(var + 1e-5f);
    float a = gamma[co] * rstd;
    ab[co] = a;
    ab[64 + co] = beta[co] - mu * a;
  }
}

// ============================================================
// K2: conv1d -> BN -> spike -> pack 64 channel bits into u64 per (t,b)
// ============================================================
__global__ __launch_bounds__(256) void k2_spike(const float* __restrict__ x,
                                                const float* __restrict__ cw,
                                                const float* __restrict__ thrp,
                                                const float* __restrict__ ab,
                                                unsigned long long* __restrict__ masks) {
  __shared__ float xLds[244 * CIN];
  __shared__ float cwLds[64 * 70];
  const int b = blockIdx.x, tile = blockIdx.y;
  const int base = tile * 240;
  for (int f = threadIdx.x; f < 244 * CIN; f += 256) {
    int u = f / CIN, ci = f - u * CIN;
    int tp = base + u - 2;
    xLds[f] = (tp >= 0 && tp < TSTEPS) ? x[((size_t)tp * NB + b) * CIN + ci] : 0.0f;
  }
  for (int f = threadIdx.x; f < 64 * 70; f += 256) cwLds[f] = cw[f];
  __syncthreads();

  const int co = threadIdx.x & 63, tq = threadIdx.x >> 6;
  const float thr = thrp[0];
  const float aC = ab[co], bC = ab[64 + co];
  float cwr[70];
#pragma unroll
  for (int s = 0; s < 70; ++s) cwr[s] = cwLds[co * 70 + s];
  float xw[5][CIN];
  const int u0 = tq * 60;
#pragma unroll
  for (int r = 0; r < 4; ++r)
#pragma unroll
    for (int ci = 0; ci < CIN; ++ci) xw[r][ci] = xLds[(u0 + r) * CIN + ci];

  const int tbase = base + tq * 60;
  for (int i5 = 0; i5 < 60; i5 += 5) {
#pragma unroll
    for (int s = 0; s < 5; ++s) {
#pragma unroll
      for (int ci = 0; ci < CIN; ++ci)
        xw[(s + 4) % 5][ci] = xLds[(u0 + i5 + s + 4) * CIN + ci];
      float y = 0.0f;
#pragma unroll
      for (int kk = 0; kk < 5; ++kk)
#pragma unroll
        for (int ci = 0; ci < CIN; ++ci)
          y += xw[(s + kk) % 5][ci] * cwr[ci * 5 + kk];
      int t = tbase + i5 + s;
      if (t < TSTEPS) {
        float bn = y * aC + bC;
        unsigned long long m = __ballot(bn - thr > 0.0f);  // lane i = channel i
        if (co == 0) masks[(size_t)t * NB + b] = m;
      }
    }
  }
}

// ============================================================
// KP: fused persistent two-layer SLSTM.
// 256 blocks = 64 groups (g = bid&63, 4 batch rows each) x 4 roles
// (q = bid>>6 = h-quarter). Each block computes BOTH layers for its
// (rows, h-quarter): weights live in registers (112 VGPR). Exactly ONE
// 4-block group barrier per phase; peers share an XCD (bid = g mod 8).
//
// Thread map (GEMM): lane = kq*16 + idx; idx = a*? -> a=idx&3 (gate type),
// hlq=idx>>2; hl = hlq*8 + wave; j = a*32+hl (128 gate rows / block);
// kq owns k with ((k>>1)&3)==kq  ->  simultaneous ds_read_b128 of A rows
// {2kq+b mod 8} land in 4 distinct bank quads: conflict-free, zero addr math.
// ============================================================
__global__ __launch_bounds__(512, 2) void kp_fused(char* ws,
    const float* __restrict__ w_ih1, const float* __restrict__ w_hh1,
    const float* __restrict__ b_ih1, const float* __restrict__ b_hh1,
    const float* __restrict__ thr1p,
    const float* __restrict__ w_ih2, const float* __restrict__ w_hh2,
    const float* __restrict__ b_ih2, const float* __restrict__ b_hh2,
    const float* __restrict__ thr2p) {
  __shared__ __align__(16) float A1[192 * 4];   // [k][row] rows of 16B
  __shared__ __align__(16) float A2[256 * 4];
  __shared__ float gateL[128 * 5];              // stride 5 breaks bank pattern
  __shared__ float biasL1[128], biasL2[128];

  const int tid = threadIdx.x;
  const int bid = blockIdx.x;
  const int g = bid & 63;          // group: peers bid = g+64k share XCD (mod 8)
  const int q = bid >> 6;          // h-quarter 0..3
  const int lane = tid & 63, wv = tid >> 6;
  const int idx = lane & 15, kq = lane >> 4;
  const int a = idx & 3, hlq = idx >> 2;
  const int hl = hlq * 8 + wv;
  const int j = a * 32 + hl;                 // gate row within block (0..127)
  const int grow = a * 128 + q * 32 + hl;    // global weight row (0..511)

  unsigned* cnt = (unsigned*)(ws + OFF_CNT) + g * 32;
  float* m1ws = (float*)(ws + OFF_M1WS);
  float* m2ws = (float*)(ws + OFF_M2WS);
  unsigned* spkw = (unsigned*)(ws + OFF_SPKW);
  float* feat = (float*)(ws + OFF_FEAT);
  const unsigned long long* masks = (const unsigned long long*)(ws + OFF_MASK);

  // ---- one-time: weights -> registers (interleaved k-partition) ----
  float wr1[48];
#pragma unroll
  for (int i = 0; i < 48; ++i) {
    int k = ((i >> 1) << 3) + (kq << 1) + (i & 1);   // k = 8m + 2kq + b
    wr1[i] = (k < 64) ? w_ih1[grow * 64 + k] : w_hh1[grow * 128 + (k - 64)];
  }
  float wr2[64];
#pragma unroll
  for (int i = 0; i < 64; ++i) {
    int k = ((i >> 1) << 3) + (kq << 1) + (i & 1);
    wr2[i] = (k < 128) ? w_ih2[grow * 128 + k] : w_hh2[grow * 128 + (k - 128)];
  }
  if (tid < 128) {
    int aa = tid >> 5, h2 = tid & 31;
    int gr = aa * 128 + q * 32 + h2;
    biasL1[tid] = b_ih1[gr] + b_hh1[gr];
    biasL2[tid] = b_ih2[gr] + b_hh2[gr];
  }
  const float thr1 = thr1p[0], thr2 = thr2p[0];
  // cell state (tid<128): cell (row cr, local h chl)
  const int cr = tid >> 5, chl = tid & 31;
  float syn1 = 0.0f, mem1 = 0.0f, syn2 = 0.0f, mem2 = 0.0f, facc = 0.0f;
  __syncthreads();

  // prefetch conv-spike mask for p=0 (row = tid&3)
  unsigned long long mrow = masks[(size_t)0 * NB + g * RG + (tid & 3)];

  for (int p = 0; p < TSTEPS; ++p) {
    // ---- stage A1: k<64 = conv spikes, k>=64 = mem1(p-1) ----
    {
      int f = tid;
#pragma unroll
      for (int pass = 0; pass < 2; ++pass, f += 512) {
        if (f < 768) {
          int k = f >> 2, e = f & 3;
          float v;
          if (k < 64) v = (float)((mrow >> k) & 1ull);
          else v = m1ws[((((p + 1) & 1) * 64 + g) * 4 + e) * 128 + (k - 64)];
          A1[f] = v;
        }
      }
    }
    __syncthreads();

    // ---- GEMM1: 128 gates x 4 rows, K=192, k-split over kq ----
    float ac0 = 0.0f, ac1 = 0.0f, ac2 = 0.0f, ac3 = 0.0f;
    {
      const float* Ab = A1 + (kq << 3);
#pragma unroll
      for (int m = 0; m < 24; ++m) {
#pragma unroll
        for (int b2 = 0; b2 < 2; ++b2) {
          float4 av = *(const float4*)(Ab + m * 32 + b2 * 4);
          float w = wr1[m * 2 + b2];
          ac0 += w * av.x; ac1 += w * av.y; ac2 += w * av.z; ac3 += w * av.w;
        }
      }
    }
    ac0 += __shfl_xor(ac0, 16); ac1 += __shfl_xor(ac1, 16);
    ac2 += __shfl_xor(ac2, 16); ac3 += __shfl_xor(ac3, 16);
    ac0 += __shfl_xor(ac0, 32); ac1 += __shfl_xor(ac1, 32);
    ac2 += __shfl_xor(ac2, 32); ac3 += __shfl_xor(ac3, 32);
    if (kq == 0) {
      gateL[j * 5 + 0] = ac0; gateL[j * 5 + 1] = ac1;
      gateL[j * 5 + 2] = ac2; gateL[j * 5 + 3] = ac3;
    }
    __syncthreads();

    // ---- cell1 + publish mem1 quarter + spk1 ballot bits ----
    if (tid < 128) {
      float g0 = biasL1[chl]       + gateL[(chl) * 5 + cr];
      float g1 = biasL1[32 + chl]  + gateL[(32 + chl) * 5 + cr];
      float g2 = biasL1[64 + chl]  + gateL[(64 + chl) * 5 + cr];
      float g3 = biasL1[96 + chl]  + gateL[(96 + chl) * 5 + cr];
      float rst = (mem1 - thr1 > 0.0f) ? thr1 : 0.0f;
      float ig = 1.0f / (1.0f + expf(-g0));
      float fg = 1.0f / (1.0f + expf(-g1));
      float gg = tanhf(g2);
      float og = 1.0f / (1.0f + expf(-g3));
      float cn = fg * syn1 + ig * gg;
      float mn = og * tanhf(cn) - rst;
      syn1 = cn; mem1 = mn;
      m1ws[(((p & 1) * 64 + g) * 4 + cr) * 128 + (q * 32 + chl)] = mn;
      unsigned long long bal = __ballot(mn - thr1 > 0.0f);
      if (lane == 0)
        spkw[(((p & 1) * 64 + g) * 4 + (wv * 2 + 0)) * 4 + q] =
            (unsigned)(bal & 0xffffffffull);
      if (lane == 32)
        spkw[(((p & 1) * 64 + g) * 4 + (wv * 2 + 1)) * 4 + q] =
            (unsigned)(bal >> 32);
    }
    __syncthreads();  // drains vmcnt: publishes visible before barrier

    // ---- the ONE group barrier per phase (4 same-XCD peers) ----
    if (tid == 0) {
      __threadfence();
      __hip_atomic_fetch_add(cnt, 1u, __ATOMIC_RELEASE, __HIP_MEMORY_SCOPE_AGENT);
      const unsigned tgt = 4u * (unsigned)(p + 1);
      while (__hip_atomic_load(cnt, __ATOMIC_RELAXED, __HIP_MEMORY_SCOPE_AGENT) < tgt)
        __builtin_amdgcn_s_sleep(1);
      __threadfence();
    }
    __syncthreads();

    // ---- prefetch next mask; stage A2: spk1(p) bits + mem2(p-1) ----
    if (p + 1 < TSTEPS) mrow = masks[(size_t)(p + 1) * NB + g * RG + (tid & 3)];
    {
      int f = tid;
#pragma unroll
      for (int pass = 0; pass < 2; ++pass, f += 512) {
        int k = f >> 2, e = f & 3;
        float v;
        if (k < 128) {
          unsigned u = spkw[(((p & 1) * 64 + g) * 4 + e) * 4 + (k >> 5)];
          v = (float)((u >> (k & 31)) & 1u);
        } else {
          v = m2ws[((((p + 1) & 1) * 64 + g) * 4 + e) * 128 + (k - 128)];
        }
        A2[f] = v;
      }
    }
    __syncthreads();

    // ---- GEMM2: 128 gates x 4 rows, K=256 ----
    ac0 = 0.0f; ac1 = 0.0f; ac2 = 0.0f; ac3 = 0.0f;
    {
      const float* Ab = A2 + (kq << 3);
#pragma unroll
      for (int m = 0; m < 32; ++m) {
#pragma unroll
        for (int b2 = 0; b2 < 2; ++b2) {
          float4 av = *(const float4*)(Ab + m * 32 + b2 * 4);
          float w = wr2[m * 2 + b2];
          ac0 += w * av.x; ac1 += w * av.y; ac2 += w * av.z; ac3 += w * av.w;
        }
      }
    }
    ac0 += __shfl_xor(ac0, 16); ac1 += __shfl_xor(ac1, 16);
    ac2 += __shfl_xor(ac2, 16); ac3 += __shfl_xor(ac3, 16);
    ac0 += __shfl_xor(ac0, 32); ac1 += __shfl_xor(ac1, 32);
    ac2 += __shfl_xor(ac2, 32); ac3 += __shfl_xor(ac3, 32);
    if (kq == 0) {
      gateL[j * 5 + 0] = ac0; gateL[j * 5 + 1] = ac1;
      gateL[j * 5 + 2] = ac2; gateL[j * 5 + 3] = ac3;
    }
    __syncthreads();

    // ---- cell2 + publish mem2 quarter + feature accum ----
    if (tid < 128) {
      float g0 = biasL2[chl]       + gateL[(chl) * 5 + cr];
      float g1 = biasL2[32 + chl]  + gateL[(32 + chl) * 5 + cr];
      float g2 = biasL2[64 + chl]  + gateL[(64 + chl) * 5 + cr];
      float g3 = biasL2[96 + chl]  + gateL[(96 + chl) * 5 + cr];
      float rst = (mem2 - thr2 > 0.0f) ? thr2 : 0.0f;
      float ig = 1.0f / (1.0f + expf(-g0));
      float fg = 1.0f / (1.0f + expf(-g1));
      float gg = tanhf(g2);
      float og = 1.0f / (1.0f + expf(-g3));
      float cn = fg * syn2 + ig * gg;
      float mn = og * tanhf(cn) - rst;
      syn2 = cn; mem2 = mn;
      m2ws[(((p & 1) * 64 + g) * 4 + cr) * 128 + (q * 32 + chl)] = mn;
      facc += mn;
    }
    // no trailing sync needed: next-phase A1 staging doesn't touch gateL,
    // and gateL rewrite happens only after the next S1 barrier.
  }

  if (tid < 128)
    feat[(g * RG + cr) * 128 + q * 32 + chl] = facc * (1.0f / (float)TSTEPS);
}

// ============================================================
// K3: head — gesture + (binary) domain_hidden -> domain
// ============================================================
__global__ __launch_bounds__(128) void k3_head(const float* __restrict__ feat,
    const float* __restrict__ gw, const float* __restrict__ gb,
    const float* __restrict__ d1w, const float* __restrict__ d1b,
    const float* __restrict__ thrdp,
    const float* __restrict__ d2w, const float* __restrict__ d2b,
    float* __restrict__ out) {
  __shared__ float fL[128];
  __shared__ float dh[64];
  const int b = blockIdx.x, t = threadIdx.x;
  fL[t] = feat[b * 128 + t];
  __syncthreads();
  if (t < 64) {
    float s = d1b[t];
    for (int k = 0; k < 128; ++k) s += d1w[t * 128 + k] * fL[k];
    dh[t] = (s - thrdp[0] > 0.0f) ? 1.0f : 0.0f;
  }
  __syncthreads();
  if (t < 8) {
    float s = gb[t];
    for (int k = 0; k < 128; ++k) s += gw[t * 128 + k] * fL[k];
    out[b * 8 + t] = s;
  }
  if (t >= 64 && t < 74) {
    const int o = t - 64;
    float s = d2b[o];
    for (int k = 0; k < 64; ++k) s += d2w[o * 64 + k] * dh[k];
    out[2048 + b * 10 + o] = s;
  }
}

// ============================================================
extern "C" void kernel_launch(void* const* d_in, const int* in_sizes, int n_in,
                              void* d_out, int out_size, void* d_ws, size_t ws_size,
                              hipStream_t stream) {
  const float* x      = (const float*)d_in[0];
  const float* conv_w = (const float*)d_in[1];
  const float* bn_g   = (const float*)d_in[2];
  const float* bn_b   = (const float*)d_in[3];
  const float* thrl1  = (const float*)d_in[4];
  const float* w_ih1  = (const float*)d_in[5];
  const float* w_hh1  = (const float*)d_in[6];
  const float* b_ih1  = (const float*)d_in[7];
  const float* b_hh1  = (const float*)d_in[8];
  const float* thr1   = (const float*)d_in[9];
  const float* w_ih2  = (const float*)d_in[10];
  const float* w_hh2  = (const float*)d_in[11];
  const float* b_ih2  = (const float*)d_in[12];
  const float* b_hh2  = (const float*)d_in[13];
  const float* thr2   = (const float*)d_in[14];
  const float* fc_g_w = (const float*)d_in[15];
  const float* fc_g_b = (const float*)d_in[16];
  const float* fc_d1w = (const float*)d_in[17];
  const float* fc_d1b = (const float*)d_in[18];
  const float* thrdom = (const float*)d_in[19];
  const float* fc_d2w = (const float*)d_in[20];
  const float* fc_d2b = (const float*)d_in[21];
  float* out = (float*)d_out;
  char* ws = (char*)d_ws;

  k0_zero<<<(ZERO_WORDS + 255) / 256, 256, 0, stream>>>((unsigned*)ws);
  k1_stats<<<dim3(NB, 9), 256, 0, stream>>>(x, conv_w, (float*)(ws + OFF_PART));
  k1b_reduce<<<1, 256, 0, stream>>>(bn_g, bn_b, (const float*)(ws + OFF_PART),
                                    (float*)(ws + OFF_AB));
  k2_spike<<<dim3(NB, 9), 256, 0, stream>>>(x, conv_w, thrl1,
                                            (const float*)(ws + OFF_AB),
                                            (unsigned long long*)(ws + OFF_MASK));
  kp_fused<<<NGRP * BPG, 512, 0, stream>>>(ws, w_ih1, w_hh1, b_ih1, b_hh1, thr1,
                                           w_ih2, w_hh2, b_ih2, b_hh2, thr2);
  k3_head<<<NB, 128, 0, stream>>>((const float*)(ws + OFF_FEAT), fc_g_w, fc_g_b,
                                  fc_d1w, fc_d1b, thrdom, fc_d2w, fc_d2b, out);
}

// Round 3
// 17681.406 us; speedup vs baseline: 1.9901x; 1.9901x over previous
//
#include <hip/hip_runtime.h>
#include <cstdint>
#include <cstddef>

// ---------------- problem constants ----------------
#define TSTEPS 2000
#define NB     256      // batch
#define HID    128
#define CIN    14
#define NGRP   64       // row groups
#define RG     4        // rows per group
#define BPG    4        // blocks per group (h-quarters, each does L1+L2)

// ---------------- workspace layout (bytes) ----------------
#define OFF_CNT   0ull                     // 64 counters * 128B = 8192
#define OFF_M1WS  8192ull                  // [2][64][4][128] f32 = 262144
#define OFF_M2WS  (OFF_M1WS + 262144ull)   // [2][64][4][128] f32
#define OFF_SPKW  (OFF_M2WS + 262144ull)   // [2][64][4][4] u32 = 8192
#define OFF_FEAT  (OFF_SPKW + 8192ull)     // [256][128] f32 = 131072
#define OFF_AB    (OFF_FEAT + 131072ull)   // a[64], b[64] = 512
#define OFF_PART  (OFF_AB   + 512ull)      // [2304][64][2] f32 = 1179648
#define OFF_MASK  (OFF_PART + 1179648ull)  // [2000][256] u64 = 4096000
#define ZERO_WORDS 133120                  // counters + m1ws + m2ws

// ============================================================
// K0: zero counters + state buffers (every launch, for graph replay)
// ============================================================
__global__ __launch_bounds__(256) void k0_zero(unsigned* ws) {
  int i = blockIdx.x * 256 + threadIdx.x;
  if (i < ZERO_WORDS) ws[i] = 0u;
}

// ============================================================
// K1: conv1d -> per-(b,tile) partial sum/sumsq for BN
// ============================================================
__global__ __launch_bounds__(256) void k1_stats(const float* __restrict__ x,
                                                const float* __restrict__ cw,
                                                float* __restrict__ part) {
  __shared__ float xLds[244 * CIN];
  __shared__ float cwLds[64 * 70];
  __shared__ float red[2][4][64];
  const int b = blockIdx.x, tile = blockIdx.y;
  const int base = tile * 240;
  for (int f = threadIdx.x; f < 244 * CIN; f += 256) {
    int u = f / CIN, ci = f - u * CIN;
    int tp = base + u - 2;
    xLds[f] = (tp >= 0 && tp < TSTEPS) ? x[((size_t)tp * NB + b) * CIN + ci] : 0.0f;
  }
  for (int f = threadIdx.x; f < 64 * 70; f += 256) cwLds[f] = cw[f];
  __syncthreads();

  const int co = threadIdx.x & 63, tq = threadIdx.x >> 6;
  float cwr[70];
#pragma unroll
  for (int s = 0; s < 70; ++s) cwr[s] = cwLds[co * 70 + s];
  float xw[5][CIN];
  const int u0 = tq * 60;
#pragma unroll
  for (int r = 0; r < 4; ++r)
#pragma unroll
    for (int ci = 0; ci < CIN; ++ci) xw[r][ci] = xLds[(u0 + r) * CIN + ci];

  float s1 = 0.0f, s2 = 0.0f;
  const int tbase = base + tq * 60;
  for (int i5 = 0; i5 < 60; i5 += 5) {
#pragma unroll
    for (int s = 0; s < 5; ++s) {
#pragma unroll
      for (int ci = 0; ci < CIN; ++ci)
        xw[(s + 4) % 5][ci] = xLds[(u0 + i5 + s + 4) * CIN + ci];
      float y = 0.0f;
#pragma unroll
      for (int kk = 0; kk < 5; ++kk)
#pragma unroll
        for (int ci = 0; ci < CIN; ++ci)
          y += xw[(s + kk) % 5][ci] * cwr[ci * 5 + kk];
      if (tbase + i5 + s < TSTEPS) { s1 += y; s2 += y * y; }
    }
  }
  red[0][tq][co] = s1; red[1][tq][co] = s2;
  __syncthreads();
  if (threadIdx.x < 64) {
    float a1 = red[0][0][co] + red[0][1][co] + red[0][2][co] + red[0][3][co];
    float a2 = red[1][0][co] + red[1][1][co] + red[1][2][co] + red[1][3][co];
    int blk = tile * NB + b;
    part[blk * 128 + co * 2 + 0] = a1;
    part[blk * 128 + co * 2 + 1] = a2;
  }
}

// K1b: deterministic fixed-order reduction of partials -> a[co], b[co]
__global__ __launch_bounds__(256) void k1b_reduce(const float* __restrict__ gamma,
                           const float* __restrict__ beta,
                           const float* __restrict__ part, float* __restrict__ ab) {
  __shared__ float red[2][4][64];
  const int co = threadIdx.x & 63, pt = threadIdx.x >> 6;
  float s1 = 0.0f, s2 = 0.0f;
  for (int blk = pt * 576; blk < pt * 576 + 576; ++blk) {
    s1 += part[blk * 128 + co * 2 + 0];
    s2 += part[blk * 128 + co * 2 + 1];
  }
  red[0][pt][co] = s1; red[1][pt][co] = s2;
  __syncthreads();
  if (threadIdx.x < 64) {
    float a1 = red[0][0][co] + red[0][1][co] + red[0][2][co] + red[0][3][co];
    float a2 = red[1][0][co] + red[1][1][co] + red[1][2][co] + red[1][3][co];
    const float N = (float)TSTEPS * (float)NB;
    float mu = a1 / N;
    float var = a2 / N - mu * mu;
    float rstd = 1.0f / sqrtf(var + 1e-5f);
    float a = gamma[co] * rstd;
    ab[co] = a;
    ab[64 + co] = beta[co] - mu * a;
  }
}

// ============================================================
// K2: conv1d -> BN -> spike -> pack 64 channel bits into u64 per (t,b)
// ============================================================
__global__ __launch_bounds__(256) void k2_spike(const float* __restrict__ x,
                                                const float* __restrict__ cw,
                                                const float* __restrict__ thrp,
                                                const float* __restrict__ ab,
                                                unsigned long long* __restrict__ masks) {
  __shared__ float xLds[244 * CIN];
  __shared__ float cwLds[64 * 70];
  const int b = blockIdx.x, tile = blockIdx.y;
  const int base = tile * 240;
  for (int f = threadIdx.x; f < 244 * CIN; f += 256) {
    int u = f / CIN, ci = f - u * CIN;
    int tp = base + u - 2;
    xLds[f] = (tp >= 0 && tp < TSTEPS) ? x[((size_t)tp * NB + b) * CIN + ci] : 0.0f;
  }
  for (int f = threadIdx.x; f < 64 * 70; f += 256) cwLds[f] = cw[f];
  __syncthreads();

  const int co = threadIdx.x & 63, tq = threadIdx.x >> 6;
  const float thr = thrp[0];
  const float aC = ab[co], bC = ab[64 + co];
  float cwr[70];
#pragma unroll
  for (int s = 0; s < 70; ++s) cwr[s] = cwLds[co * 70 + s];
  float xw[5][CIN];
  const int u0 = tq * 60;
#pragma unroll
  for (int r = 0; r < 4; ++r)
#pragma unroll
    for (int ci = 0; ci < CIN; ++ci) xw[r][ci] = xLds[(u0 + r) * CIN + ci];

  const int tbase = base + tq * 60;
  for (int i5 = 0; i5 < 60; i5 += 5) {
#pragma unroll
    for (int s = 0; s < 5; ++s) {
#pragma unroll
      for (int ci = 0; ci < CIN; ++ci)
        xw[(s + 4) % 5][ci] = xLds[(u0 + i5 + s + 4) * CIN + ci];
      float y = 0.0f;
#pragma unroll
      for (int kk = 0; kk < 5; ++kk)
#pragma unroll
        for (int ci = 0; ci < CIN; ++ci)
          y += xw[(s + kk) % 5][ci] * cwr[ci * 5 + kk];
      int t = tbase + i5 + s;
      if (t < TSTEPS) {
        float bn = y * aC + bC;
        unsigned long long m = __ballot(bn - thr > 0.0f);  // lane i = channel i
        if (co == 0) masks[(size_t)t * NB + b] = m;
      }
    }
  }
}

// ============================================================
// KP: fused persistent two-layer SLSTM. FENCE-FREE SYNC:
//  - state exchange via RELAXED AGENT atomics (bypass L1/L2 -> coherence
//    point; no dirty L2 lines, so no wbl2/inv needed -> no __threadfence).
//  - barrier = plain atomicAdd (relaxed) + relaxed agent spin load.
//  - ordering: __syncthreads drains vmcnt(0) (stores ACKed at L3) before
//    the counter add; consumer reads only after observing the add.
// 256 blocks = 64 groups (g = bid&63, 4 batch rows) x 4 roles (h-quarter).
// Weights in registers (112 VGPR). ONE group barrier per phase.
// ============================================================
__global__ __launch_bounds__(512, 2) void kp_fused(char* ws,
    const float* __restrict__ w_ih1, const float* __restrict__ w_hh1,
    const float* __restrict__ b_ih1, const float* __restrict__ b_hh1,
    const float* __restrict__ thr1p,
    const float* __restrict__ w_ih2, const float* __restrict__ w_hh2,
    const float* __restrict__ b_ih2, const float* __restrict__ b_hh2,
    const float* __restrict__ thr2p) {
  __shared__ __align__(16) float A1[192 * 4];   // [k][row] rows of 16B
  __shared__ __align__(16) float A2[256 * 4];
  __shared__ float gateL[128 * 5];              // stride 5 breaks bank pattern
  __shared__ float biasL1[128], biasL2[128];

  const int tid = threadIdx.x;
  const int bid = blockIdx.x;
  const int g = bid & 63;          // group; peers bid = g+64k
  const int q = bid >> 6;          // h-quarter 0..3
  const int lane = tid & 63, wv = tid >> 6;
  const int idx = lane & 15, kq = lane >> 4;
  const int a = idx & 3, hlq = idx >> 2;
  const int hl = hlq * 8 + wv;
  const int j = a * 32 + hl;                 // gate row within block (0..127)
  const int grow = a * 128 + q * 32 + hl;    // global weight row (0..511)

  unsigned* cnt = (unsigned*)(ws + OFF_CNT) + g * 32;
  float* m1ws = (float*)(ws + OFF_M1WS);
  float* m2ws = (float*)(ws + OFF_M2WS);
  unsigned* spkw = (unsigned*)(ws + OFF_SPKW);
  float* feat = (float*)(ws + OFF_FEAT);
  const unsigned long long* masks = (const unsigned long long*)(ws + OFF_MASK);

  // ---- one-time: weights -> registers (interleaved k-partition) ----
  float wr1[48];
#pragma unroll
  for (int i = 0; i < 48; ++i) {
    int k = ((i >> 1) << 3) + (kq << 1) + (i & 1);   // k = 8m + 2kq + b
    wr1[i] = (k < 64) ? w_ih1[grow * 64 + k] : w_hh1[grow * 128 + (k - 64)];
  }
  float wr2[64];
#pragma unroll
  for (int i = 0; i < 64; ++i) {
    int k = ((i >> 1) << 3) + (kq << 1) + (i & 1);
    wr2[i] = (k < 128) ? w_ih2[grow * 128 + k] : w_hh2[grow * 128 + (k - 128)];
  }
  if (tid < 128) {
    int aa = tid >> 5, h2 = tid & 31;
    int gr = aa * 128 + q * 32 + h2;
    biasL1[tid] = b_ih1[gr] + b_hh1[gr];
    biasL2[tid] = b_ih2[gr] + b_hh2[gr];
  }
  const float thr1 = thr1p[0], thr2 = thr2p[0];
  // cell state (tid<128): cell (row cr, local h chl)
  const int cr = tid >> 5, chl = tid & 31;
  float syn1 = 0.0f, mem1 = 0.0f, syn2 = 0.0f, mem2 = 0.0f, facc = 0.0f;
  __syncthreads();

  // prefetch conv-spike mask for p=0 (row = tid&3)
  unsigned long long mrow = masks[(size_t)0 * NB + g * RG + (tid & 3)];

  for (int p = 0; p < TSTEPS; ++p) {
    // ---- stage A1: k<64 = conv spikes, k>=64 = mem1(p-1) ----
    {
      int f = tid;
#pragma unroll
      for (int pass = 0; pass < 2; ++pass, f += 512) {
        if (f < 768) {
          int k = f >> 2, e = f & 3;
          float v;
          if (k < 64) v = (float)((mrow >> k) & 1ull);
          else v = __hip_atomic_load(
                     &m1ws[((((p + 1) & 1) * 64 + g) * 4 + e) * 128 + (k - 64)],
                     __ATOMIC_RELAXED, __HIP_MEMORY_SCOPE_AGENT);
          A1[f] = v;
        }
      }
    }
    __syncthreads();

    // ---- GEMM1: 128 gates x 4 rows, K=192, k-split over kq ----
    float ac0 = 0.0f, ac1 = 0.0f, ac2 = 0.0f, ac3 = 0.0f;
    {
      const float* Ab = A1 + (kq << 3);
#pragma unroll
      for (int m = 0; m < 24; ++m) {
#pragma unroll
        for (int b2 = 0; b2 < 2; ++b2) {
          float4 av = *(const float4*)(Ab + m * 32 + b2 * 4);
          float w = wr1[m * 2 + b2];
          ac0 += w * av.x; ac1 += w * av.y; ac2 += w * av.z; ac3 += w * av.w;
        }
      }
    }
    ac0 += __shfl_xor(ac0, 16); ac1 += __shfl_xor(ac1, 16);
    ac2 += __shfl_xor(ac2, 16); ac3 += __shfl_xor(ac3, 16);
    ac0 += __shfl_xor(ac0, 32); ac1 += __shfl_xor(ac1, 32);
    ac2 += __shfl_xor(ac2, 32); ac3 += __shfl_xor(ac3, 32);
    if (kq == 0) {
      gateL[j * 5 + 0] = ac0; gateL[j * 5 + 1] = ac1;
      gateL[j * 5 + 2] = ac2; gateL[j * 5 + 3] = ac3;
    }
    __syncthreads();

    // ---- cell1 + publish mem1 quarter + spk1 ballot bits ----
    if (tid < 128) {
      float g0 = biasL1[chl]       + gateL[(chl) * 5 + cr];
      float g1 = biasL1[32 + chl]  + gateL[(32 + chl) * 5 + cr];
      float g2 = biasL1[64 + chl]  + gateL[(64 + chl) * 5 + cr];
      float g3 = biasL1[96 + chl]  + gateL[(96 + chl) * 5 + cr];
      float rst = (mem1 - thr1 > 0.0f) ? thr1 : 0.0f;
      float ig = 1.0f / (1.0f + expf(-g0));
      float fg = 1.0f / (1.0f + expf(-g1));
      float gg = tanhf(g2);
      float og = 1.0f / (1.0f + expf(-g3));
      float cn = fg * syn1 + ig * gg;
      float mn = og * tanhf(cn) - rst;
      syn1 = cn; mem1 = mn;
      __hip_atomic_store(&m1ws[(((p & 1) * 64 + g) * 4 + cr) * 128 + (q * 32 + chl)],
                         mn, __ATOMIC_RELAXED, __HIP_MEMORY_SCOPE_AGENT);
      unsigned long long bal = __ballot(mn - thr1 > 0.0f);
      if (lane == 0)
        __hip_atomic_store(&spkw[(((p & 1) * 64 + g) * 4 + (wv * 2 + 0)) * 4 + q],
                           (unsigned)(bal & 0xffffffffull),
                           __ATOMIC_RELAXED, __HIP_MEMORY_SCOPE_AGENT);
      if (lane == 32)
        __hip_atomic_store(&spkw[(((p & 1) * 64 + g) * 4 + (wv * 2 + 1)) * 4 + q],
                           (unsigned)(bal >> 32),
                           __ATOMIC_RELAXED, __HIP_MEMORY_SCOPE_AGENT);
    }
    __syncthreads();  // drains vmcnt(0): publishes ACKed before the add below

    // ---- the ONE group barrier per phase (fence-free) ----
    if (tid == 0) {
      atomicAdd(cnt, 1u);  // relaxed, device scope; no cache maintenance
      const unsigned tgt = 4u * (unsigned)(p + 1);
      while (__hip_atomic_load(cnt, __ATOMIC_RELAXED, __HIP_MEMORY_SCOPE_AGENT) < tgt)
        __builtin_amdgcn_s_sleep(1);
    }
    __syncthreads();

    // ---- prefetch next mask; stage A2: spk1(p) bits + mem2(p-1) ----
    if (p + 1 < TSTEPS) mrow = masks[(size_t)(p + 1) * NB + g * RG + (tid & 3)];
    {
      int f = tid;
#pragma unroll
      for (int pass = 0; pass < 2; ++pass, f += 512) {
        int k = f >> 2, e = f & 3;
        float v;
        if (k < 128) {
          unsigned u = __hip_atomic_load(
              &spkw[(((p & 1) * 64 + g) * 4 + e) * 4 + (k >> 5)],
              __ATOMIC_RELAXED, __HIP_MEMORY_SCOPE_AGENT);
          v = (float)((u >> (k & 31)) & 1u);
        } else {
          v = __hip_atomic_load(
              &m2ws[((((p + 1) & 1) * 64 + g) * 4 + e) * 128 + (k - 128)],
              __ATOMIC_RELAXED, __HIP_MEMORY_SCOPE_AGENT);
        }
        A2[f] = v;
      }
    }
    __syncthreads();

    // ---- GEMM2: 128 gates x 4 rows, K=256 ----
    ac0 = 0.0f; ac1 = 0.0f; ac2 = 0.0f; ac3 = 0.0f;
    {
      const float* Ab = A2 + (kq << 3);
#pragma unroll
      for (int m = 0; m < 32; ++m) {
#pragma unroll
        for (int b2 = 0; b2 < 2; ++b2) {
          float4 av = *(const float4*)(Ab + m * 32 + b2 * 4);
          float w = wr2[m * 2 + b2];
          ac0 += w * av.x; ac1 += w * av.y; ac2 += w * av.z; ac3 += w * av.w;
        }
      }
    }
    ac0 += __shfl_xor(ac0, 16); ac1 += __shfl_xor(ac1, 16);
    ac2 += __shfl_xor(ac2, 16); ac3 += __shfl_xor(ac3, 16);
    ac0 += __shfl_xor(ac0, 32); ac1 += __shfl_xor(ac1, 32);
    ac2 += __shfl_xor(ac2, 32); ac3 += __shfl_xor(ac3, 32);
    if (kq == 0) {
      gateL[j * 5 + 0] = ac0; gateL[j * 5 + 1] = ac1;
      gateL[j * 5 + 2] = ac2; gateL[j * 5 + 3] = ac3;
    }
    __syncthreads();

    // ---- cell2 + publish mem2 quarter + feature accum ----
    if (tid < 128) {
      float g0 = biasL2[chl]       + gateL[(chl) * 5 + cr];
      float g1 = biasL2[32 + chl]  + gateL[(32 + chl) * 5 + cr];
      float g2 = biasL2[64 + chl]  + gateL[(64 + chl) * 5 + cr];
      float g3 = biasL2[96 + chl]  + gateL[(96 + chl) * 5 + cr];
      float rst = (mem2 - thr2 > 0.0f) ? thr2 : 0.0f;
      float ig = 1.0f / (1.0f + expf(-g0));
      float fg = 1.0f / (1.0f + expf(-g1));
      float gg = tanhf(g2);
      float og = 1.0f / (1.0f + expf(-g3));
      float cn = fg * syn2 + ig * gg;
      float mn = og * tanhf(cn) - rst;
      syn2 = cn; mem2 = mn;
      __hip_atomic_store(&m2ws[(((p & 1) * 64 + g) * 4 + cr) * 128 + (q * 32 + chl)],
                         mn, __ATOMIC_RELAXED, __HIP_MEMORY_SCOPE_AGENT);
      facc += mn;
    }
    // no trailing sync needed: next-phase A1 staging doesn't touch gateL,
    // and gateL rewrite happens only after the next barrier.
  }

  if (tid < 128)
    feat[(g * RG + cr) * 128 + q * 32 + chl] = facc * (1.0f / (float)TSTEPS);
}

// ============================================================
// K3: head — gesture + (binary) domain_hidden -> domain
// ============================================================
__global__ __launch_bounds__(128) void k3_head(const float* __restrict__ feat,
    const float* __restrict__ gw, const float* __restrict__ gb,
    const float* __restrict__ d1w, const float* __restrict__ d1b,
    const float* __restrict__ thrdp,
    const float* __restrict__ d2w, const float* __restrict__ d2b,
    float* __restrict__ out) {
  __shared__ float fL[128];
  __shared__ float dh[64];
  const int b = blockIdx.x, t = threadIdx.x;
  fL[t] = feat[b * 128 + t];
  __syncthreads();
  if (t < 64) {
    float s = d1b[t];
    for (int k = 0; k < 128; ++k) s += d1w[t * 128 + k] * fL[k];
    dh[t] = (s - thrdp[0] > 0.0f) ? 1.0f : 0.0f;
  }
  __syncthreads();
  if (t < 8) {
    float s = gb[t];
    for (int k = 0; k < 128; ++k) s += gw[t * 128 + k] * fL[k];
    out[b * 8 + t] = s;
  }
  if (t >= 64 && t < 74) {
    const int o = t - 64;
    float s = d2b[o];
    for (int k = 0; k < 64; ++k) s += d2w[o * 64 + k] * dh[k];
    out[2048 + b * 10 + o] = s;
  }
}

// ============================================================
extern "C" void kernel_launch(void* const* d_in, const int* in_sizes, int n_in,
                              void* d_out, int out_size, void* d_ws, size_t ws_size,
                              hipStream_t stream) {
  const float* x      = (const float*)d_in[0];
  const float* conv_w = (const float*)d_in[1];
  const float* bn_g   = (const float*)d_in[2];
  const float* bn_b   = (const float*)d_in[3];
  const float* thrl1  = (const float*)d_in[4];
  const float* w_ih1  = (const float*)d_in[5];
  const float* w_hh1  = (const float*)d_in[6];
  const float* b_ih1  = (const float*)d_in[7];
  const float* b_hh1  = (const float*)d_in[8];
  const float* thr1   = (const float*)d_in[9];
  const float* w_ih2  = (const float*)d_in[10];
  const float* w_hh2  = (const float*)d_in[11];
  const float* b_ih2  = (const float*)d_in[12];
  const float* b_hh2  = (const float*)d_in[13];
  const float* thr2   = (const float*)d_in[14];
  const float* fc_g_w = (const float*)d_in[15];
  const float* fc_g_b = (const float*)d_in[16];
  const float* fc_d1w = (const float*)d_in[17];
  const float* fc_d1b = (const float*)d_in[18];
  const float* thrdom = (const float*)d_in[19];
  const float* fc_d2w = (const float*)d_in[20];
  const float* fc_d2b = (const float*)d_in[21];
  float* out = (float*)d_out;
  char* ws = (char*)d_ws;

  k0_zero<<<(ZERO_WORDS + 255) / 256, 256, 0, stream>>>((unsigned*)ws);
  k1_stats<<<dim3(NB, 9), 256, 0, stream>>>(x, conv_w, (float*)(ws + OFF_PART));
  k1b_reduce<<<1, 256, 0, stream>>>(bn_g, bn_b, (const float*)(ws + OFF_PART),
                                    (float*)(ws + OFF_AB));
  k2_spike<<<dim3(NB, 9), 256, 0, stream>>>(x, conv_w, thrl1,
                                            (const float*)(ws + OFF_AB),
                                            (unsigned long long*)(ws + OFF_MASK));
  kp_fused<<<NGRP * BPG, 512, 0, stream>>>(ws, w_ih1, w_hh1, b_ih1, b_hh1, thr1,
                                           w_ih2, w_hh2, b_ih2, b_hh2, thr2);
  k3_head<<<NB, 128, 0, stream>>>((const float*)(ws + OFF_FEAT), fc_g_w, fc_g_b,
                                  fc_d1w, fc_d1b, thrdom, fc_d2w, fc_d2b, out);
}

// Round 4
// 17460.268 us; speedup vs baseline: 2.0153x; 1.0127x over previous
//
#include <hip/hip_runtime.h>
#include <cstdint>
#include <cstddef>

// ---------------- problem constants ----------------
#define TSTEPS 2000
#define NB     256      // batch
#define HID    128
#define CIN    14
#define NGRP   64       // row groups
#define RG     4        // rows per group
#define BPG    4        // blocks per group (h-quarters, each does L1+L2)

// ---------------- workspace layout (bytes) ----------------
#define OFF_CNT   0ull                     // 256 flags * 32B = 8192
#define OFF_M1WS  8192ull                  // [2][64][4][128] f32 = 262144
#define OFF_M2WS  (OFF_M1WS + 262144ull)   // [2][64][4][128] f32
#define OFF_SPKW  (OFF_M2WS + 262144ull)   // [2][64][4][4] u32 = 8192
#define OFF_FEAT  (OFF_SPKW + 8192ull)     // [256][128] f32 = 131072
#define OFF_AB    (OFF_FEAT + 131072ull)   // a[64], b[64] = 512
#define OFF_PART  (OFF_AB   + 512ull)      // [2304][64][2] f32 = 1179648
#define OFF_MASK  (OFF_PART + 1179648ull)  // [2000][256] u64 = 4096000
#define ZERO_WORDS 133120                  // flags + m1ws + m2ws

// ============================================================
// K0: zero flags + state buffers (every launch, for graph replay)
// ============================================================
__global__ __launch_bounds__(256) void k0_zero(unsigned* ws) {
  int i = blockIdx.x * 256 + threadIdx.x;
  if (i < ZERO_WORDS) ws[i] = 0u;
}

// ============================================================
// K1: conv1d -> per-(b,tile) partial sum/sumsq for BN
// ============================================================
__global__ __launch_bounds__(256) void k1_stats(const float* __restrict__ x,
                                                const float* __restrict__ cw,
                                                float* __restrict__ part) {
  __shared__ float xLds[244 * CIN];
  __shared__ float cwLds[64 * 70];
  __shared__ float red[2][4][64];
  const int b = blockIdx.x, tile = blockIdx.y;
  const int base = tile * 240;
  for (int f = threadIdx.x; f < 244 * CIN; f += 256) {
    int u = f / CIN, ci = f - u * CIN;
    int tp = base + u - 2;
    xLds[f] = (tp >= 0 && tp < TSTEPS) ? x[((size_t)tp * NB + b) * CIN + ci] : 0.0f;
  }
  for (int f = threadIdx.x; f < 64 * 70; f += 256) cwLds[f] = cw[f];
  __syncthreads();

  const int co = threadIdx.x & 63, tq = threadIdx.x >> 6;
  float cwr[70];
#pragma unroll
  for (int s = 0; s < 70; ++s) cwr[s] = cwLds[co * 70 + s];
  float xw[5][CIN];
  const int u0 = tq * 60;
#pragma unroll
  for (int r = 0; r < 4; ++r)
#pragma unroll
    for (int ci = 0; ci < CIN; ++ci) xw[r][ci] = xLds[(u0 + r) * CIN + ci];

  float s1 = 0.0f, s2 = 0.0f;
  const int tbase = base + tq * 60;
  for (int i5 = 0; i5 < 60; i5 += 5) {
#pragma unroll
    for (int s = 0; s < 5; ++s) {
#pragma unroll
      for (int ci = 0; ci < CIN; ++ci)
        xw[(s + 4) % 5][ci] = xLds[(u0 + i5 + s + 4) * CIN + ci];
      float y = 0.0f;
#pragma unroll
      for (int kk = 0; kk < 5; ++kk)
#pragma unroll
        for (int ci = 0; ci < CIN; ++ci)
          y += xw[(s + kk) % 5][ci] * cwr[ci * 5 + kk];
      if (tbase + i5 + s < TSTEPS) { s1 += y; s2 += y * y; }
    }
  }
  red[0][tq][co] = s1; red[1][tq][co] = s2;
  __syncthreads();
  if (threadIdx.x < 64) {
    float a1 = red[0][0][co] + red[0][1][co] + red[0][2][co] + red[0][3][co];
    float a2 = red[1][0][co] + red[1][1][co] + red[1][2][co] + red[1][3][co];
    int blk = tile * NB + b;
    part[blk * 128 + co * 2 + 0] = a1;
    part[blk * 128 + co * 2 + 1] = a2;
  }
}

// K1b: deterministic fixed-order reduction of partials -> a[co], b[co]
__global__ __launch_bounds__(256) void k1b_reduce(const float* __restrict__ gamma,
                           const float* __restrict__ beta,
                           const float* __restrict__ part, float* __restrict__ ab) {
  __shared__ float red[2][4][64];
  const int co = threadIdx.x & 63, pt = threadIdx.x >> 6;
  float s1 = 0.0f, s2 = 0.0f;
  for (int blk = pt * 576; blk < pt * 576 + 576; ++blk) {
    s1 += part[blk * 128 + co * 2 + 0];
    s2 += part[blk * 128 + co * 2 + 1];
  }
  red[0][pt][co] = s1; red[1][pt][co] = s2;
  __syncthreads();
  if (threadIdx.x < 64) {
    float a1 = red[0][0][co] + red[0][1][co] + red[0][2][co] + red[0][3][co];
    float a2 = red[1][0][co] + red[1][1][co] + red[1][2][co] + red[1][3][co];
    const float N = (float)TSTEPS * (float)NB;
    float mu = a1 / N;
    float var = a2 / N - mu * mu;
    float rstd = 1.0f / sqrtf(var + 1e-5f);
    float a = gamma[co] * rstd;
    ab[co] = a;
    ab[64 + co] = beta[co] - mu * a;
  }
}

// ============================================================
// K2: conv1d -> BN -> spike -> pack 64 channel bits into u64 per (t,b)
// ============================================================
__global__ __launch_bounds__(256) void k2_spike(const float* __restrict__ x,
                                                const float* __restrict__ cw,
                                                const float* __restrict__ thrp,
                                                const float* __restrict__ ab,
                                                unsigned long long* __restrict__ masks) {
  __shared__ float xLds[244 * CIN];
  __shared__ float cwLds[64 * 70];
  const int b = blockIdx.x, tile = blockIdx.y;
  const int base = tile * 240;
  for (int f = threadIdx.x; f < 244 * CIN; f += 256) {
    int u = f / CIN, ci = f - u * CIN;
    int tp = base + u - 2;
    xLds[f] = (tp >= 0 && tp < TSTEPS) ? x[((size_t)tp * NB + b) * CIN + ci] : 0.0f;
  }
  for (int f = threadIdx.x; f < 64 * 70; f += 256) cwLds[f] = cw[f];
  __syncthreads();

  const int co = threadIdx.x & 63, tq = threadIdx.x >> 6;
  const float thr = thrp[0];
  const float aC = ab[co], bC = ab[64 + co];
  float cwr[70];
#pragma unroll
  for (int s = 0; s < 70; ++s) cwr[s] = cwLds[co * 70 + s];
  float xw[5][CIN];
  const int u0 = tq * 60;
#pragma unroll
  for (int r = 0; r < 4; ++r)
#pragma unroll
    for (int ci = 0; ci < CIN; ++ci) xw[r][ci] = xLds[(u0 + r) * CIN + ci];

  const int tbase = base + tq * 60;
  for (int i5 = 0; i5 < 60; i5 += 5) {
#pragma unroll
    for (int s = 0; s < 5; ++s) {
#pragma unroll
      for (int ci = 0; ci < CIN; ++ci)
        xw[(s + 4) % 5][ci] = xLds[(u0 + i5 + s + 4) * CIN + ci];
      float y = 0.0f;
#pragma unroll
      for (int kk = 0; kk < 5; ++kk)
#pragma unroll
        for (int ci = 0; ci < CIN; ++ci)
          y += xw[(s + kk) % 5][ci] * cwr[ci * 5 + kk];
      int t = tbase + i5 + s;
      if (t < TSTEPS) {
        float bn = y * aC + bC;
        unsigned long long m = __ballot(bn - thr > 0.0f);  // lane i = channel i
        if (co == 0) masks[(size_t)t * NB + b] = m;
      }
    }
  }
}

// ============================================================
// KP: fused persistent two-layer SLSTM, SOFTWARE-PIPELINED:
// phase p computes L1 step p AND L2 step p-1. All inputs of phase p
// (m1(p-1), spk1(p-1), m2(p-2)) are guarded by the ONE barrier at end
// of phase p-1 -> single load burst, both GEMMs back-to-back, one
// drain+flag+spin per phase.
// Sync is fence-free: relaxed-agent atomics (L1/L2-bypassing) for all
// exchanged data; __syncthreads drains vmcnt before the epoch-flag
// store; peers spin on the 4 flags (no RMW).
// Numerics are bit-identical to round 3 (same k-interleave, same shfl
// reduce order, same cell code) -> absmax must stay 0.0.
// ============================================================
__global__ __launch_bounds__(512) void kp_fused(char* ws,
    const float* __restrict__ w_ih1, const float* __restrict__ w_hh1,
    const float* __restrict__ b_ih1, const float* __restrict__ b_hh1,
    const float* __restrict__ thr1p,
    const float* __restrict__ w_ih2, const float* __restrict__ w_hh2,
    const float* __restrict__ b_ih2, const float* __restrict__ b_hh2,
    const float* __restrict__ thr2p) {
  __shared__ __align__(16) float A1[192 * 4];   // [k][row] rows of 16B
  __shared__ __align__(16) float A2[256 * 4];
  __shared__ float gate1L[128 * 5];             // stride 5 breaks bank pattern
  __shared__ float gate2L[128 * 5];
  __shared__ float biasL1[128], biasL2[128];

  const int tid = threadIdx.x;
  const int bid = blockIdx.x;
  const int g = bid & 63;          // group; peers bid = g+64k (same XCD mod 8)
  const int q = bid >> 6;          // h-quarter 0..3
  const int lane = tid & 63, wv = tid >> 6;
  const int idx = lane & 15, kq = lane >> 4;
  const int a = idx & 3, hlq = idx >> 2;
  const int hl = hlq * 8 + wv;
  const int j = a * 32 + hl;                 // gate row within block (0..127)
  const int grow = a * 128 + q * 32 + hl;    // global weight row (0..511)

  unsigned* flags = (unsigned*)(ws + OFF_CNT);   // [(g*4+q)*8], 32B apart
  float* m1ws = (float*)(ws + OFF_M1WS);
  float* m2ws = (float*)(ws + OFF_M2WS);
  unsigned* spkw = (unsigned*)(ws + OFF_SPKW);
  float* feat = (float*)(ws + OFF_FEAT);
  const unsigned long long* masks = (const unsigned long long*)(ws + OFF_MASK);

  // ---- one-time: weights -> registers (interleaved k-partition) ----
  float wr1[48];
#pragma unroll
  for (int i = 0; i < 48; ++i) {
    int k = ((i >> 1) << 3) + (kq << 1) + (i & 1);   // k = 8m + 2kq + b
    wr1[i] = (k < 64) ? w_ih1[grow * 64 + k] : w_hh1[grow * 128 + (k - 64)];
  }
  float wr2[64];
#pragma unroll
  for (int i = 0; i < 64; ++i) {
    int k = ((i >> 1) << 3) + (kq << 1) + (i & 1);
    wr2[i] = (k < 128) ? w_ih2[grow * 128 + k] : w_hh2[grow * 128 + (k - 128)];
  }
  if (tid < 128) {
    int aa = tid >> 5, h2 = tid & 31;
    int gr = aa * 128 + q * 32 + h2;
    biasL1[tid] = b_ih1[gr] + b_hh1[gr];
    biasL2[tid] = b_ih2[gr] + b_hh2[gr];
  }
  const float thr1 = thr1p[0], thr2 = thr2p[0];
  // cell state (tid<128): cell (row cr, local h chl)
  const int cr = tid >> 5, chl = tid & 31;
  float syn1 = 0.0f, mem1 = 0.0f, syn2 = 0.0f, mem2 = 0.0f, facc = 0.0f;
  __syncthreads();

  // conv-spike mask for step 0 (row = tid&3)
  unsigned long long mrow = masks[(size_t)0 * NB + g * RG + (tid & 3)];

  for (int p = 0; p <= TSTEPS; ++p) {
    const int rb1 = (p + 1) & 1;   // parity of p-1
    const int wb = p & 1;

    // ---- single load burst: stage A1 (L1 step p) and A2 (L2 step p-1) ----
    {  // A1 entries 0..511: k<64 mask bits, 64..127 m1(p-1)
      int k = tid >> 2, e = tid & 3;
      float v;
      if (k < 64) v = (float)((mrow >> k) & 1ull);
      else v = __hip_atomic_load(&m1ws[((rb1 * 64 + g) * 4 + e) * 128 + (k - 64)],
                                 __ATOMIC_RELAXED, __HIP_MEMORY_SCOPE_AGENT);
      A1[tid] = v;
    }
    {  // A1 entries 512..767: k in [128,192) -> m1(p-1)
      int f = tid + 512;
      if (f < 768) {
        int k = f >> 2, e = f & 3;
        float v = __hip_atomic_load(&m1ws[((rb1 * 64 + g) * 4 + e) * 128 + (k - 64)],
                                    __ATOMIC_RELAXED, __HIP_MEMORY_SCOPE_AGENT);
        A1[f] = v;
      }
    }
    {  // A2 entries 0..511: k<128 -> spk1(p-1) bits
      int k = tid >> 2, e = tid & 3;
      unsigned u = __hip_atomic_load(&spkw[((rb1 * 64 + g) * 4 + e) * 4 + (k >> 5)],
                                     __ATOMIC_RELAXED, __HIP_MEMORY_SCOPE_AGENT);
      A2[tid] = (float)((u >> (k & 31)) & 1u);
    }
    {  // A2 entries 512..1023: k in [128,256) -> m2(p-2)
      int f = tid + 512;
      int k = f >> 2, e = f & 3;
      float v = __hip_atomic_load(&m2ws[((wb * 64 + g) * 4 + e) * 128 + (k - 128)],
                                  __ATOMIC_RELAXED, __HIP_MEMORY_SCOPE_AGENT);
      A2[f] = v;
    }
    // prefetch next conv mask (static input, no guard dependency)
    if (p + 1 < TSTEPS) mrow = masks[(size_t)(p + 1) * NB + g * RG + (tid & 3)];
    __syncthreads();

    // ---- GEMM1: 128 gates x 4 rows, K=192, k-split over kq ----
    {
      float ac0 = 0.0f, ac1 = 0.0f, ac2 = 0.0f, ac3 = 0.0f;
      const float* Ab = A1 + (kq << 3);
#pragma unroll
      for (int m = 0; m < 24; ++m) {
#pragma unroll
        for (int b2 = 0; b2 < 2; ++b2) {
          float4 av = *(const float4*)(Ab + m * 32 + b2 * 4);
          float w = wr1[m * 2 + b2];
          ac0 += w * av.x; ac1 += w * av.y; ac2 += w * av.z; ac3 += w * av.w;
        }
      }
      ac0 += __shfl_xor(ac0, 16); ac1 += __shfl_xor(ac1, 16);
      ac2 += __shfl_xor(ac2, 16); ac3 += __shfl_xor(ac3, 16);
      ac0 += __shfl_xor(ac0, 32); ac1 += __shfl_xor(ac1, 32);
      ac2 += __shfl_xor(ac2, 32); ac3 += __shfl_xor(ac3, 32);
      if (kq == 0) {
        gate1L[j * 5 + 0] = ac0; gate1L[j * 5 + 1] = ac1;
        gate1L[j * 5 + 2] = ac2; gate1L[j * 5 + 3] = ac3;
      }
    }
    // ---- GEMM2: 128 gates x 4 rows, K=256 ----
    {
      float ac0 = 0.0f, ac1 = 0.0f, ac2 = 0.0f, ac3 = 0.0f;
      const float* Ab = A2 + (kq << 3);
#pragma unroll
      for (int m = 0; m < 32; ++m) {
#pragma unroll
        for (int b2 = 0; b2 < 2; ++b2) {
          float4 av = *(const float4*)(Ab + m * 32 + b2 * 4);
          float w = wr2[m * 2 + b2];
          ac0 += w * av.x; ac1 += w * av.y; ac2 += w * av.z; ac3 += w * av.w;
        }
      }
      ac0 += __shfl_xor(ac0, 16); ac1 += __shfl_xor(ac1, 16);
      ac2 += __shfl_xor(ac2, 16); ac3 += __shfl_xor(ac3, 16);
      ac0 += __shfl_xor(ac0, 32); ac1 += __shfl_xor(ac1, 32);
      ac2 += __shfl_xor(ac2, 32); ac3 += __shfl_xor(ac3, 32);
      if (kq == 0) {
        gate2L[j * 5 + 0] = ac0; gate2L[j * 5 + 1] = ac1;
        gate2L[j * 5 + 2] = ac2; gate2L[j * 5 + 3] = ac3;
      }
    }
    __syncthreads();

    // ---- cell1 (step p) + publish m1(p), spk1(p) ----
    if (tid < 128 && p < TSTEPS) {
      float g0 = biasL1[chl]       + gate1L[(chl) * 5 + cr];
      float g1 = biasL1[32 + chl]  + gate1L[(32 + chl) * 5 + cr];
      float g2 = biasL1[64 + chl]  + gate1L[(64 + chl) * 5 + cr];
      float g3 = biasL1[96 + chl]  + gate1L[(96 + chl) * 5 + cr];
      float rst = (mem1 - thr1 > 0.0f) ? thr1 : 0.0f;
      float ig = 1.0f / (1.0f + expf(-g0));
      float fg = 1.0f / (1.0f + expf(-g1));
      float gg = tanhf(g2);
      float og = 1.0f / (1.0f + expf(-g3));
      float cn = fg * syn1 + ig * gg;
      float mn = og * tanhf(cn) - rst;
      syn1 = cn; mem1 = mn;
      __hip_atomic_store(&m1ws[((wb * 64 + g) * 4 + cr) * 128 + (q * 32 + chl)],
                         mn, __ATOMIC_RELAXED, __HIP_MEMORY_SCOPE_AGENT);
      unsigned long long bal = __ballot(mn - thr1 > 0.0f);
      if (lane == 0)
        __hip_atomic_store(&spkw[((wb * 64 + g) * 4 + (wv * 2 + 0)) * 4 + q],
                           (unsigned)(bal & 0xffffffffull),
                           __ATOMIC_RELAXED, __HIP_MEMORY_SCOPE_AGENT);
      if (lane == 32)
        __hip_atomic_store(&spkw[((wb * 64 + g) * 4 + (wv * 2 + 1)) * 4 + q],
                           (unsigned)(bal >> 32),
                           __ATOMIC_RELAXED, __HIP_MEMORY_SCOPE_AGENT);
    }
    // ---- cell2 (step p-1) + publish m2(p-1) + feature accum ----
    if (tid < 128 && p >= 1) {
      float g0 = biasL2[chl]       + gate2L[(chl) * 5 + cr];
      float g1 = biasL2[32 + chl]  + gate2L[(32 + chl) * 5 + cr];
      float g2 = biasL2[64 + chl]  + gate2L[(64 + chl) * 5 + cr];
      float g3 = biasL2[96 + chl]  + gate2L[(96 + chl) * 5 + cr];
      float rst = (mem2 - thr2 > 0.0f) ? thr2 : 0.0f;
      float ig = 1.0f / (1.0f + expf(-g0));
      float fg = 1.0f / (1.0f + expf(-g1));
      float gg = tanhf(g2);
      float og = 1.0f / (1.0f + expf(-g3));
      float cn = fg * syn2 + ig * gg;
      float mn = og * tanhf(cn) - rst;
      syn2 = cn; mem2 = mn;
      __hip_atomic_store(&m2ws[((rb1 * 64 + g) * 4 + cr) * 128 + (q * 32 + chl)],
                         mn, __ATOMIC_RELAXED, __HIP_MEMORY_SCOPE_AGENT);
      facc += mn;
    }
    __syncthreads();  // drains vmcnt(0): all publishes ACKed at coherence point

    // ---- ONE distributed-flag barrier per phase (fence-free, no RMW) ----
    if (p < TSTEPS) {
      if (tid == 0)
        __hip_atomic_store(&flags[(g * 4 + q) * 8], (unsigned)(p + 1),
                           __ATOMIC_RELAXED, __HIP_MEMORY_SCOPE_AGENT);
      if (tid < 4) {
        while (__hip_atomic_load(&flags[(g * 4 + tid) * 8],
                                 __ATOMIC_RELAXED, __HIP_MEMORY_SCOPE_AGENT)
               < (unsigned)(p + 1))
          __builtin_amdgcn_s_sleep(1);
      }
      __syncthreads();
    }
  }

  if (tid < 128)
    feat[(g * RG + cr) * 128 + q * 32 + chl] = facc * (1.0f / (float)TSTEPS);
}

// ============================================================
// K3: head — gesture + (binary) domain_hidden -> domain
// ============================================================
__global__ __launch_bounds__(128) void k3_head(const float* __restrict__ feat,
    const float* __restrict__ gw, const float* __restrict__ gb,
    const float* __restrict__ d1w, const float* __restrict__ d1b,
    const float* __restrict__ thrdp,
    const float* __restrict__ d2w, const float* __restrict__ d2b,
    float* __restrict__ out) {
  __shared__ float fL[128];
  __shared__ float dh[64];
  const int b = blockIdx.x, t = threadIdx.x;
  fL[t] = feat[b * 128 + t];
  __syncthreads();
  if (t < 64) {
    float s = d1b[t];
    for (int k = 0; k < 128; ++k) s += d1w[t * 128 + k] * fL[k];
    dh[t] = (s - thrdp[0] > 0.0f) ? 1.0f : 0.0f;
  }
  __syncthreads();
  if (t < 8) {
    float s = gb[t];
    for (int k = 0; k < 128; ++k) s += gw[t * 128 + k] * fL[k];
    out[b * 8 + t] = s;
  }
  if (t >= 64 && t < 74) {
    const int o = t - 64;
    float s = d2b[o];
    for (int k = 0; k < 64; ++k) s += d2w[o * 64 + k] * dh[k];
    out[2048 + b * 10 + o] = s;
  }
}

// ============================================================
extern "C" void kernel_launch(void* const* d_in, const int* in_sizes, int n_in,
                              void* d_out, int out_size, void* d_ws, size_t ws_size,
                              hipStream_t stream) {
  const float* x      = (const float*)d_in[0];
  const float* conv_w = (const float*)d_in[1];
  const float* bn_g   = (const float*)d_in[2];
  const float* bn_b   = (const float*)d_in[3];
  const float* thrl1  = (const float*)d_in[4];
  const float* w_ih1  = (const float*)d_in[5];
  const float* w_hh1  = (const float*)d_in[6];
  const float* b_ih1  = (const float*)d_in[7];
  const float* b_hh1  = (const float*)d_in[8];
  const float* thr1   = (const float*)d_in[9];
  const float* w_ih2  = (const float*)d_in[10];
  const float* w_hh2  = (const float*)d_in[11];
  const float* b_ih2  = (const float*)d_in[12];
  const float* b_hh2  = (const float*)d_in[13];
  const float* thr2   = (const float*)d_in[14];
  const float* fc_g_w = (const float*)d_in[15];
  const float* fc_g_b = (const float*)d_in[16];
  const float* fc_d1w = (const float*)d_in[17];
  const float* fc_d1b = (const float*)d_in[18];
  const float* thrdom = (const float*)d_in[19];
  const float* fc_d2w = (const float*)d_in[20];
  const float* fc_d2b = (const float*)d_in[21];
  float* out = (float*)d_out;
  char* ws = (char*)d_ws;

  k0_zero<<<(ZERO_WORDS + 255) / 256, 256, 0, stream>>>((unsigned*)ws);
  k1_stats<<<dim3(NB, 9), 256, 0, stream>>>(x, conv_w, (float*)(ws + OFF_PART));
  k1b_reduce<<<1, 256, 0, stream>>>(bn_g, bn_b, (const float*)(ws + OFF_PART),
                                    (float*)(ws + OFF_AB));
  k2_spike<<<dim3(NB, 9), 256, 0, stream>>>(x, conv_w, thrl1,
                                            (const float*)(ws + OFF_AB),
                                            (unsigned long long*)(ws + OFF_MASK));
  kp_fused<<<NGRP * BPG, 512, 0, stream>>>(ws, w_ih1, w_hh1, b_ih1, b_hh1, thr1,
                                           w_ih2, w_hh2, b_ih2, b_hh2, thr2);
  k3_head<<<NB, 128, 0, stream>>>((const float*)(ws + OFF_FEAT), fc_g_w, fc_g_b,
                                  fc_d1w, fc_d1b, thrdom, fc_d2w, fc_d2b, out);
}